// Round 18
// baseline (197.890 us; speedup 1.0000x reference)
//
#include <hip/hip_runtime.h>
#include <stdint.h>

typedef unsigned short u16;
typedef unsigned int   u32;
typedef short  short8  __attribute__((ext_vector_type(8)));
typedef float  f32x4   __attribute__((ext_vector_type(4)));
typedef u16    u16x4   __attribute__((ext_vector_type(4)));
typedef u32    u32x4   __attribute__((ext_vector_type(4)));

#define LAMBDA_INIT   0.25550906759096927f
#define ONE_MINUS_LI  0.7444909324090307f
// (1/sqrt(64)) * log2(e): puts QK^T scores directly in exp2 units
#define QSCALE        0.18033688011112043f

__device__ __forceinline__ u16 f2bf(float f) {
  union { float f; u32 u; } v; v.f = f;
  u32 r = v.u + 0x7fffu + ((v.u >> 16) & 1u);  // RTNE
  return (u16)(r >> 16);
}

// pack two f32 -> bf16x2 by truncation (a -> low16, b -> high16)
__device__ __forceinline__ u32 packtr(float a, float b) {
  return (__builtin_bit_cast(u32, a) >> 16) | (__builtin_bit_cast(u32, b) & 0xffff0000u);
}

// raw v_exp_f32: D = 2^S0 (vetted r7/r8)
__device__ __forceinline__ float expv(float x) {
  float r; asm("v_exp_f32 %0, %1" : "=v"(r) : "v"(x)); return r;
}

__device__ __forceinline__ void gload16(const void* g, void* l) {
  __builtin_amdgcn_global_load_lds(
      (const __attribute__((address_space(1))) void*)g,
      (__attribute__((address_space(3))) void*)l, 16, 0, 0);
}

// ---------------- f32 -> bf16 conversion: ONE launch, 12 x 1M segments ----
__global__ __launch_bounds__(256) void k_cvt12(
    const float* __restrict__ x,  const float* __restrict__ wq1,
    const float* __restrict__ wq2, const float* __restrict__ wk1,
    const float* __restrict__ wk2, const float* __restrict__ wv,
    const float* __restrict__ wc,
    u16* __restrict__ xb, u16* __restrict__ wall, u16* __restrict__ wcb) {
  const int seg = blockIdx.y;
  const float* s;
  u16* d;
  if (seg < 4)       { s = x + (size_t)seg * 1048576;        d = xb + (size_t)seg * 1048576; }
  else if (seg == 4) { s = wq1;                              d = wall; }
  else if (seg == 5) { s = wq2;                              d = wall + 1048576; }
  else if (seg == 6) { s = wk1;                              d = wall + 2097152; }
  else if (seg == 7) { s = wk2;                              d = wall + 3145728; }
  else if (seg < 10) { s = wv + (size_t)(seg - 8) * 1048576; d = wall + 4194304 + (size_t)(seg - 8) * 1048576; }
  else               { s = wc + (size_t)(seg - 10) * 1048576; d = wcb + (size_t)(seg - 10) * 1048576; }
  int i = (blockIdx.x * 256 + threadIdx.x) * 4;
  float4 v = *(const float4*)(s + i);
  u16x4 o = { f2bf(v.x), f2bf(v.y), f2bf(v.z), f2bf(v.w) };
  *(u16x4*)(d + i) = o;
}

// ---------------- shared 128x128 bf16 GEMM tile (256 thr) ----------------
__device__ __forceinline__ void gemm_tile_128(
    const u16* __restrict__ A, const u16* __restrict__ Bm, int K,
    int m0, int n0, char* smem, f32x4 acc[4][4]) {
  const int tid = threadIdx.x;
  const int l = tid & 63, w = tid >> 6, g = l >> 4, q = l & 15;
  const int wm = w >> 1, wn = w & 1;
  char* As = smem;
  char* Bs = smem + 16384;
#pragma unroll
  for (int mi = 0; mi < 4; mi++)
#pragma unroll
    for (int ni = 0; ni < 4; ni++) acc[mi][ni] = (f32x4){0.f, 0.f, 0.f, 0.f};

  const int nkt = K >> 6;
  for (int kt = 0; kt < nkt; ++kt) {
    __syncthreads();
#pragma unroll
    for (int i = 0; i < 4; i++) {
      int cc = i * 256 + tid;
      int row = cc >> 3, off = cc & 7;
      int sw = (off * 16) ^ ((row & 7) << 4);
      gload16((const char*)A + ((size_t)(m0 + row) * K + kt * 64) * 2 + sw, As + cc * 16);
      gload16((const char*)Bm + ((size_t)(n0 + row) * K + kt * 64) * 2 + sw, Bs + cc * 16);
    }
    __syncthreads();
#pragma unroll
    for (int ks = 0; ks < 2; ++ks) {
      short8 af[4], bf[4];
#pragma unroll
      for (int mi = 0; mi < 4; mi++) {
        int row = wm * 64 + mi * 16 + q;
        af[mi] = *(const short8*)(As + ((row * 128 + ks * 64 + g * 16) ^ ((row & 7) << 4)));
      }
#pragma unroll
      for (int ni = 0; ni < 4; ni++) {
        int row = wn * 64 + ni * 16 + q;
        bf[ni] = *(const short8*)(Bs + ((row * 128 + ks * 64 + g * 16) ^ ((row & 7) << 4)));
      }
#pragma unroll
      for (int mi = 0; mi < 4; mi++)
#pragma unroll
        for (int ni = 0; ni < 4; ni++)
          acc[mi][ni] = __builtin_amdgcn_mfma_f32_16x16x32_bf16(af[mi], bf[ni], acc[mi][ni], 0, 0, 0);
    }
  }
}

// ---------------- fused QKV projection ----------------
// q/k -> [bh][T][64] (q pre-scaled). V -> x32-fragment-packed layout Vf (u16):
// V[t][d] at bh*262144 + (t>>6)*8192 + (((t>>5)&1)*8 + (d>>4))*512
//                      + ((t>>3)&3)*128 + (d&15)*8 + (t&7)
__global__ __launch_bounds__(256) void k_gemm_qkv(
    const u16* __restrict__ xb, const u16* __restrict__ wall,
    u16* __restrict__ q1, u16* __restrict__ q2,
    u16* __restrict__ k1, u16* __restrict__ k2,
    u16* __restrict__ vt) {
  __shared__ __align__(16) char smem[32768];
  f32x4 acc[4][4];
  const int n0 = blockIdx.x * 128, m0 = blockIdx.y * 128;
  gemm_tile_128(xb, wall, 1024, m0, n0, smem, acc);

  const int l = threadIdx.x & 63, w = threadIdx.x >> 6, g = l >> 4, q = l & 15;
  const int wm = w >> 1, wn = w & 1;
  const int seg = n0 >> 10;
  const float sc = (seg < 2) ? QSCALE : 1.0f;
  u16* qk = (seg == 0) ? q1 : (seg == 1) ? q2 : (seg == 2) ? k1 : k2;
#pragma unroll
  for (int mi = 0; mi < 4; mi++)
#pragma unroll
    for (int ni = 0; ni < 4; ni++) {
      int row0 = m0 + wm * 64 + mi * 16 + 4 * g;  // token, == 0 mod 4
      int col = n0 + wn * 64 + ni * 16 + q;
      int bb = row0 >> 11;
      if (seg < 4) {
        int h = (col >> 6) & 15, hd = col & 63;
#pragma unroll
        for (int r = 0; r < 4; r++) {
          int t = (row0 + r) & 2047;
          qk[(((size_t)bb * 16 + h) * 2048 + t) * 64 + hd] = f2bf(acc[mi][ni][r] * sc);
        }
      } else {
        int nv = col - 4096, hh = nv >> 7, d = nv & 127;
        int t = row0 & 2047;
        u16x4 pv;
#pragma unroll
        for (int r = 0; r < 4; r++) pv[r] = f2bf(acc[mi][ni][r]);
        size_t addr = (size_t)(bb * 16 + hh) * 262144 + (size_t)(t >> 6) * 8192
                    + (size_t)(((((t >> 5) & 1) * 8 + (d >> 4)) * 512)
                               + ((t >> 3) & 3) * 128 + (d & 15) * 8 + (t & 7));
        *(u16x4*)(vt + addr) = pv;
      }
    }
}

// ---------------- differential flash attention + sub-LN ----------------
// 1-D grid of 1024 blocks, 256 thr (4 waves): one block per 64-row q-tile.
// Mapping (dispatch model: fid&7 -> XCD, then round-robin CUs in XCD):
//   xcd = fid&7, p = (fid>>3)&31 (CU slot), k = fid>>8 (round), t8 = p>>2
//   tile: k0: 31-t8  k1: t8  k2: 23-t8  k3: 8+t8   -> per-CU tile sum = 62
//   => EXACTLY 132 chunks per CU (r17's mapping had 104..160, 35% tail)
//   bh = xcd*4 + (p&3): 4 bh per XCD (L2-resident KV) AND all 4 blocks on
//   one CU share the same bh (L1 reuse). Bijective per (bh, tile).
// KV chunk = 32, LDS 2x16KB -> 4 blocks/CU x 4 waves = 16 waves/CU.
__global__ __launch_bounds__(256) void k_attn(
    const u16* __restrict__ q1p, const u16* __restrict__ q2p,
    const u16* __restrict__ k1p, const u16* __restrict__ k2p,
    const u16* __restrict__ vfp,
    const float* __restrict__ lq1, const float* __restrict__ lk1,
    const float* __restrict__ lq2, const float* __restrict__ lk2,
    u16* __restrict__ ybp) {
  __shared__ __align__(16) char smem[32768];  // 2 x (K1 4K | K2 4K | Vf 8K)
  const int fid = blockIdx.x;
  const int xcd = fid & 7;
  const int p = (fid >> 3) & 31;
  const int k = fid >> 8;                      // round 0..3
  const int t8 = p >> 2;
  const int tile = (k == 0) ? (31 - t8) : (k == 1) ? t8
                 : (k == 2) ? (23 - t8) : (8 + t8);
  const int bh = xcd * 4 + (p & 3);
  const int b = bh >> 4, h = bh & 15;
  const int tid = threadIdx.x, w = tid >> 6, l = tid & 63, g = l >> 4, q = l & 15;
  const int nchunk = 2 * tile + 2;             // 32-kv chunks
  const int qrow = tile * 64 + w * 16 + q;

  float a1 = lq1[h * 64 + l] * lk1[h * 64 + l];
  float a2 = lq2[h * 64 + l] * lk2[h * 64 + l];
#pragma unroll
  for (int off = 32; off; off >>= 1) {
    a1 += __shfl_xor(a1, off);
    a2 += __shfl_xor(a2, off);
  }
  const float lam = expf(a1) - expf(a2) + LAMBDA_INIT;

  short8 qf[2][2];
  {
    size_t qoff = ((size_t)bh * 2048 + qrow) * 64;
#pragma unroll
    for (int ks = 0; ks < 2; ++ks) {
      qf[0][ks] = *(const short8*)(q1p + qoff + ks * 32 + g * 8);
      qf[1][ks] = *(const short8*)(q2p + qoff + ks * 32 + g * 8);
    }
  }
  f32x4 o[2][8];
  float lsum[2] = {0.f, 0.f};
#pragma unroll
  for (int s = 0; s < 2; s++)
#pragma unroll
    for (int mt = 0; mt < 8; mt++) o[s][mt] = (f32x4){0.f, 0.f, 0.f, 0.f};

  auto stage_kv = [&](char* sb, int kv0) {
    // K1,K2: 32 rows x 128B = 4KB each, one pass of 256 thr x 16B
    int kv = tid >> 3, off = tid & 7;
    int sw = (off * 16) ^ ((kv & 7) << 4);
    size_t rb = ((size_t)bh * 2048 + kv0 + kv) * 128;
    gload16((const char*)k1p + rb + sw, sb + tid * 16);
    gload16((const char*)k2p + rb + sw, sb + 4096 + tid * 16);
    // Vf 32-kv half-block: 8KB contiguous
    const char* vsrc = (const char*)vfp + (size_t)bh * 524288
                     + (size_t)(kv0 >> 6) * 16384 + (size_t)((kv0 >> 5) & 1) * 8192;
    gload16(vsrc + tid * 16, sb + 8192 + tid * 16);
    gload16(vsrc + 4096 + tid * 16, sb + 12288 + tid * 16);
  };

  stage_kv(smem, 0);

  for (int i = 0; i < nchunk; ++i) {
    char* sb = smem + (i & 1) * 16384;
    // stage[i] was issued one full compute phase ago -> cheap drain
    asm volatile("s_waitcnt vmcnt(0)" ::: "memory");
    __builtin_amdgcn_s_barrier();
    if (i + 1 < nchunk) stage_kv(smem + ((i + 1) & 1) * 16384, (i + 1) * 32);

    const int kv0 = i * 32;
    const bool diag = (i >= nchunk - 2);

    u32 pk[2][4];
#pragma unroll
    for (int s = 0; s < 2; ++s) {
      const char* Ks = sb + s * 4096;
      f32x4 s0 = {0.f, 0.f, 0.f, 0.f}, s1 = {0.f, 0.f, 0.f, 0.f};
#pragma unroll
      for (int ks = 0; ks < 2; ++ks) {
        short8 af0 = *(const short8*)(Ks + ((q * 128 + ks * 64 + g * 16) ^ ((q & 7) << 4)));
        short8 af1 = *(const short8*)(Ks + (((16 + q) * 128 + ks * 64 + g * 16) ^ ((q & 7) << 4)));
        s0 = __builtin_amdgcn_mfma_f32_16x16x32_bf16(af0, qf[s][ks], s0, 0, 0, 0);
        s1 = __builtin_amdgcn_mfma_f32_16x16x32_bf16(af1, qf[s][ks], s1, 0, 0, 0);
      }
      const int kb0 = kv0 + 4 * g, kb1 = kb0 + 16;
      if (diag) {
#pragma unroll
        for (int r = 0; r < 4; r++) {
          s0[r] = (kb0 + r > qrow) ? -1e30f : s0[r];
          s1[r] = (kb1 + r > qrow) ? -1e30f : s1[r];
        }
      }
      float p0[4], p1[4], rs = 0.f;
#pragma unroll
      for (int r = 0; r < 4; r++) {
        p0[r] = expv(s0[r]);
        p1[r] = expv(s1[r]);
        rs += p0[r] + p1[r];
      }
      lsum[s] += rs;  // per-lane partial; reduced in epilogue

      u32 pk0[2] = { packtr(p0[0], p0[1]), packtr(p0[2], p0[3]) };
      u32 pk1[2] = { packtr(p1[0], p1[1]), packtr(p1[2], p1[3]) };
      int srcA = q + (g & 1) * 32;
      int srcB = srcA + 16;
      u32 xa0 = (u32)__shfl((int)pk0[0], srcA), xa1 = (u32)__shfl((int)pk0[1], srcA);
      u32 xa2 = (u32)__shfl((int)pk0[0], srcB), xa3 = (u32)__shfl((int)pk0[1], srcB);
      u32 xb0 = (u32)__shfl((int)pk1[0], srcA), xb1 = (u32)__shfl((int)pk1[1], srcA);
      u32 xb2 = (u32)__shfl((int)pk1[0], srcB), xb3 = (u32)__shfl((int)pk1[1], srcB);
      bool lo = (g < 2);
      pk[s][0] = lo ? xa0 : xb0;
      pk[s][1] = lo ? xa1 : xb1;
      pk[s][2] = lo ? xa2 : xb2;
      pk[s][3] = lo ? xa3 : xb3;
    }
    u32x4 t0 = {pk[0][0], pk[0][1], pk[0][2], pk[0][3]};
    u32x4 t1 = {pk[1][0], pk[1][1], pk[1][2], pk[1][3]};
    short8 pf0 = __builtin_bit_cast(short8, t0);
    short8 pf1 = __builtin_bit_cast(short8, t1);
    // PV: x32 MFMA, V A-fragments are lane-linear b128 reads (conflict-free)
    const char* Vb = sb + 8192 + l * 16;
    __builtin_amdgcn_s_setprio(1);   // T5: favor MFMA cluster (multi-block/CU)
#pragma unroll
    for (int mt = 0; mt < 8; ++mt) {
      short8 vf = *(const short8*)(Vb + mt * 1024);
      o[0][mt] = __builtin_amdgcn_mfma_f32_16x16x32_bf16(vf, pf0, o[0][mt], 0, 0, 0);
      o[1][mt] = __builtin_amdgcn_mfma_f32_16x16x32_bf16(vf, pf1, o[1][mt], 0, 0, 0);
    }
    __builtin_amdgcn_s_setprio(0);
  }

  // epilogue: diff, sub-LN over 128 dims, scale, store bf16
  float l0 = lsum[0]; l0 += __shfl_xor(l0, 16); l0 += __shfl_xor(l0, 32);
  float l1 = lsum[1]; l1 += __shfl_xor(l1, 16); l1 += __shfl_xor(l1, 32);
  const float inv0 = 1.f / l0, inv1 = 1.f / l1;
  float sum = 0.f, ssq = 0.f;
#pragma unroll
  for (int mt = 0; mt < 8; ++mt)
#pragma unroll
    for (int r = 0; r < 4; r++) {
      float y = o[0][mt][r] * inv0 - lam * (o[1][mt][r] * inv1);
      o[0][mt][r] = y;
      sum += y;
      ssq += y * y;
    }
  sum += __shfl_xor(sum, 16); sum += __shfl_xor(sum, 32);
  ssq += __shfl_xor(ssq, 16); ssq += __shfl_xor(ssq, 32);
  const float mean = sum * (1.f / 128.f);
  const float var = ssq * (1.f / 128.f) - mean * mean;
  const float rstd = rsqrtf(var + 1e-5f) * ONE_MINUS_LI;
  u16* dst = ybp + ((size_t)(b * 2048 + qrow)) * 2048 + h * 128;
#pragma unroll
  for (int mt = 0; mt < 8; ++mt) {
    u16x4 pv;
#pragma unroll
    for (int r = 0; r < 4; r++) pv[r] = f2bf((o[0][mt][r] - mean) * rstd);
    *(u16x4*)(dst + mt * 16 + 4 * g) = pv;
  }
}

// ---------------- output projection (512 thr, 8 waves, 2 waves/SIMD) ------
__global__ __launch_bounds__(512) void k_gemm_out(
    const u16* __restrict__ yb, const u16* __restrict__ wcb,
    float* __restrict__ out) {
  __shared__ __align__(16) char smem[32768];
  const int tid = threadIdx.x;
  const int l = tid & 63, w = tid >> 6, g = l >> 4, q = l & 15;
  const int wm = w >> 1, wn = w & 1;   // wm 0..3 (32-row strips), wn 0..1 (64-col)
  const int n0 = blockIdx.x * 128, m0 = blockIdx.y * 128;
  char* As = smem;
  char* Bs = smem + 16384;
  f32x4 acc[2][4];
#pragma unroll
  for (int mi = 0; mi < 2; mi++)
#pragma unroll
    for (int ni = 0; ni < 4; ni++) acc[mi][ni] = (f32x4){0.f, 0.f, 0.f, 0.f};

  for (int kt = 0; kt < 32; ++kt) {
    __syncthreads();
#pragma unroll
    for (int i = 0; i < 2; i++) {
      int cc = i * 512 + tid;
      int row = cc >> 3, off = cc & 7;
      int sw = (off * 16) ^ ((row & 7) << 4);
      gload16((const char*)yb + ((size_t)(m0 + row) * 2048 + kt * 64) * 2 + sw, As + cc * 16);
      gload16((const char*)wcb + ((size_t)(n0 + row) * 2048 + kt * 64) * 2 + sw, Bs + cc * 16);
    }
    __syncthreads();
#pragma unroll
    for (int ks = 0; ks < 2; ++ks) {
      short8 af[2], bf[4];
#pragma unroll
      for (int mi = 0; mi < 2; mi++) {
        int row = wm * 32 + mi * 16 + q;
        af[mi] = *(const short8*)(As + ((row * 128 + ks * 64 + g * 16) ^ ((row & 7) << 4)));
      }
#pragma unroll
      for (int ni = 0; ni < 4; ni++) {
        int row = wn * 64 + ni * 16 + q;
        bf[ni] = *(const short8*)(Bs + ((row * 128 + ks * 64 + g * 16) ^ ((row & 7) << 4)));
      }
#pragma unroll
      for (int mi = 0; mi < 2; mi++)
#pragma unroll
        for (int ni = 0; ni < 4; ni++)
          acc[mi][ni] = __builtin_amdgcn_mfma_f32_16x16x32_bf16(af[mi], bf[ni], acc[mi][ni], 0, 0, 0);
    }
  }
#pragma unroll
  for (int mi = 0; mi < 2; mi++)
#pragma unroll
    for (int ni = 0; ni < 4; ni++)
#pragma unroll
      for (int r = 0; r < 4; r++) {
        int row = m0 + wm * 32 + mi * 16 + 4 * g + r;
        int col = n0 + wn * 64 + ni * 16 + q;
        out[(size_t)row * 1024 + col] = acc[mi][ni][r];
      }
}

extern "C" void kernel_launch(void* const* d_in, const int* in_sizes, int n_in,
                              void* d_out, int out_size, void* d_ws, size_t ws_size,
                              hipStream_t stream) {
  const float* x   = (const float*)d_in[0];
  const float* Wq1 = (const float*)d_in[1];
  const float* Wq2 = (const float*)d_in[2];
  const float* Wk1 = (const float*)d_in[3];
  const float* Wk2 = (const float*)d_in[4];
  const float* Wv  = (const float*)d_in[5];
  const float* Wc  = (const float*)d_in[6];
  const float* lq1 = (const float*)d_in[7];
  const float* lk1 = (const float*)d_in[8];
  const float* lq2 = (const float*)d_in[9];
  const float* lk2 = (const float*)d_in[10];

  char* ws = (char*)d_ws;
  u16* xb   = (u16*)(ws);                    // 8 MB
  u16* wall = (u16*)(ws + 8388608);          // 12 MB
  u16* wcb  = (u16*)(ws + 20971520);         // 4 MB
  u16* q1   = (u16*)(ws + 25165824);         // 8 MB
  u16* q2   = (u16*)(ws + 33554432);         // 8 MB
  u16* k1   = (u16*)(ws + 41943040);         // 8 MB
  u16* k2   = (u16*)(ws + 50331648);         // 8 MB
  u16* vt   = (u16*)(ws + 58720256);         // 16 MB (x32-fragment-packed Vf)
  u16* yb   = (u16*)(ws + 75497472);         // 16 MB

  k_cvt12<<<dim3(1024, 12), 256, 0, stream>>>(x, Wq1, Wq2, Wk1, Wk2, Wv, Wc,
                                              xb, wall, wcb);
  k_gemm_qkv<<<dim3(48, 32), 256, 0, stream>>>(xb, wall, q1, q2, k1, k2, vt);
  k_attn<<<1024, 256, 0, stream>>>(q1, q2, k1, k2, vt,
                                   lq1, lk1, lq2, lk2, yb);
  k_gemm_out<<<dim3(8, 32), 512, 0, stream>>>(yb, wcb, (float*)d_out);
}

// Round 19
// 188.999 us; speedup vs baseline: 1.0470x; 1.0470x over previous
//
#include <hip/hip_runtime.h>
#include <stdint.h>

typedef unsigned short u16;
typedef unsigned int   u32;
typedef short  short8  __attribute__((ext_vector_type(8)));
typedef float  f32x4   __attribute__((ext_vector_type(4)));
typedef u16    u16x4   __attribute__((ext_vector_type(4)));
typedef u32    u32x4   __attribute__((ext_vector_type(4)));

#define LAMBDA_INIT   0.25550906759096927f
#define ONE_MINUS_LI  0.7444909324090307f
// (1/sqrt(64)) * log2(e): puts QK^T scores directly in exp2 units
#define QSCALE        0.18033688011112043f

__device__ __forceinline__ u16 f2bf(float f) {
  union { float f; u32 u; } v; v.f = f;
  u32 r = v.u + 0x7fffu + ((v.u >> 16) & 1u);  // RTNE
  return (u16)(r >> 16);
}

// pack two f32 -> bf16x2 by truncation (a -> low16, b -> high16)
__device__ __forceinline__ u32 packtr(float a, float b) {
  return (__builtin_bit_cast(u32, a) >> 16) | (__builtin_bit_cast(u32, b) & 0xffff0000u);
}

// raw v_exp_f32: D = 2^S0 (vetted r7/r8)
__device__ __forceinline__ float expv(float x) {
  float r; asm("v_exp_f32 %0, %1" : "=v"(r) : "v"(x)); return r;
}

__device__ __forceinline__ void gload16(const void* g, void* l) {
  __builtin_amdgcn_global_load_lds(
      (const __attribute__((address_space(1))) void*)g,
      (__attribute__((address_space(3))) void*)l, 16, 0, 0);
}

// ---------------- f32 -> bf16 conversion: ONE launch, 12 x 1M segments ----
__global__ __launch_bounds__(256) void k_cvt12(
    const float* __restrict__ x,  const float* __restrict__ wq1,
    const float* __restrict__ wq2, const float* __restrict__ wk1,
    const float* __restrict__ wk2, const float* __restrict__ wv,
    const float* __restrict__ wc,
    u16* __restrict__ xb, u16* __restrict__ wall, u16* __restrict__ wcb) {
  const int seg = blockIdx.y;
  const float* s;
  u16* d;
  if (seg < 4)       { s = x + (size_t)seg * 1048576;        d = xb + (size_t)seg * 1048576; }
  else if (seg == 4) { s = wq1;                              d = wall; }
  else if (seg == 5) { s = wq2;                              d = wall + 1048576; }
  else if (seg == 6) { s = wk1;                              d = wall + 2097152; }
  else if (seg == 7) { s = wk2;                              d = wall + 3145728; }
  else if (seg < 10) { s = wv + (size_t)(seg - 8) * 1048576; d = wall + 4194304 + (size_t)(seg - 8) * 1048576; }
  else               { s = wc + (size_t)(seg - 10) * 1048576; d = wcb + (size_t)(seg - 10) * 1048576; }
  int i = (blockIdx.x * 256 + threadIdx.x) * 4;
  float4 v = *(const float4*)(s + i);
  u16x4 o = { f2bf(v.x), f2bf(v.y), f2bf(v.z), f2bf(v.w) };
  *(u16x4*)(d + i) = o;
}

// ---------------- fused QKV projection (pipelined 128x128 tile) ----------
// Single-barrier pipeline (attn-proven): prologue stage(buf0); per K-step:
// vmcnt(0) [loads issued one full compute phase ago] -> s_barrier ->
// issue stage[kt+1] -> compute[kt]. Loads stay in flight across compute.
// q/k -> [bh][T][64] (q pre-scaled). V -> x32-fragment-packed layout Vf (u16):
// V[t][d] at bh*262144 + (t>>6)*8192 + (((t>>5)&1)*8 + (d>>4))*512
//                      + ((t>>3)&3)*128 + (d&15)*8 + (t&7)
__global__ __launch_bounds__(256) void k_gemm_qkv(
    const u16* __restrict__ xb, const u16* __restrict__ wall,
    u16* __restrict__ q1, u16* __restrict__ q2,
    u16* __restrict__ k1, u16* __restrict__ k2,
    u16* __restrict__ vt) {
  __shared__ __align__(16) char smem[65536];   // 2 x (As 16K | Bs 16K)
  const int tid = threadIdx.x;
  const int l = tid & 63, w = tid >> 6, g = l >> 4, q = l & 15;
  const int wm = w >> 1, wn = w & 1;
  const int n0 = blockIdx.x * 128, m0 = blockIdx.y * 128;
  f32x4 acc[4][4];
#pragma unroll
  for (int mi = 0; mi < 4; mi++)
#pragma unroll
    for (int ni = 0; ni < 4; ni++) acc[mi][ni] = (f32x4){0.f, 0.f, 0.f, 0.f};

  auto stage = [&](char* sb, int kt) {
#pragma unroll
    for (int i = 0; i < 4; i++) {
      int cc = i * 256 + tid;
      int row = cc >> 3, off = cc & 7;
      int sw = (off * 16) ^ ((row & 7) << 4);
      gload16((const char*)xb + ((size_t)(m0 + row) * 1024 + kt * 64) * 2 + sw, sb + cc * 16);
      gload16((const char*)wall + ((size_t)(n0 + row) * 1024 + kt * 64) * 2 + sw, sb + 16384 + cc * 16);
    }
  };

  stage(smem, 0);
  for (int kt = 0; kt < 16; ++kt) {
    asm volatile("s_waitcnt vmcnt(0)" ::: "memory");
    __builtin_amdgcn_s_barrier();
    if (kt + 1 < 16) stage(smem + ((kt + 1) & 1) * 32768, kt + 1);
    const char* As = smem + (kt & 1) * 32768;
    const char* Bs = As + 16384;
#pragma unroll
    for (int ks = 0; ks < 2; ++ks) {
      short8 af[4], bf[4];
#pragma unroll
      for (int mi = 0; mi < 4; mi++) {
        int row = wm * 64 + mi * 16 + q;
        af[mi] = *(const short8*)(As + ((row * 128 + ks * 64 + g * 16) ^ ((row & 7) << 4)));
      }
#pragma unroll
      for (int ni = 0; ni < 4; ni++) {
        int row = wn * 64 + ni * 16 + q;
        bf[ni] = *(const short8*)(Bs + ((row * 128 + ks * 64 + g * 16) ^ ((row & 7) << 4)));
      }
#pragma unroll
      for (int mi = 0; mi < 4; mi++)
#pragma unroll
        for (int ni = 0; ni < 4; ni++)
          acc[mi][ni] = __builtin_amdgcn_mfma_f32_16x16x32_bf16(af[mi], bf[ni], acc[mi][ni], 0, 0, 0);
    }
  }

  const int seg = n0 >> 10;
  const float sc = (seg < 2) ? QSCALE : 1.0f;
  u16* qk = (seg == 0) ? q1 : (seg == 1) ? q2 : (seg == 2) ? k1 : k2;
#pragma unroll
  for (int mi = 0; mi < 4; mi++)
#pragma unroll
    for (int ni = 0; ni < 4; ni++) {
      int row0 = m0 + wm * 64 + mi * 16 + 4 * g;  // token, == 0 mod 4
      int col = n0 + wn * 64 + ni * 16 + q;
      int bb = row0 >> 11;
      if (seg < 4) {
        int h = (col >> 6) & 15, hd = col & 63;
#pragma unroll
        for (int r = 0; r < 4; r++) {
          int t = (row0 + r) & 2047;
          qk[(((size_t)bb * 16 + h) * 2048 + t) * 64 + hd] = f2bf(acc[mi][ni][r] * sc);
        }
      } else {
        int nv = col - 4096, hh = nv >> 7, d = nv & 127;
        int t = row0 & 2047;
        u16x4 pv;
#pragma unroll
        for (int r = 0; r < 4; r++) pv[r] = f2bf(acc[mi][ni][r]);
        size_t addr = (size_t)(bb * 16 + hh) * 262144 + (size_t)(t >> 6) * 8192
                    + (size_t)(((((t >> 5) & 1) * 8 + (d >> 4)) * 512)
                               + ((t >> 3) & 3) * 128 + (d & 15) * 8 + (t & 7));
        *(u16x4*)(vt + addr) = pv;
      }
    }
}

// ---------------- differential flash attention + sub-LN (r18 verbatim) ----
__global__ __launch_bounds__(256) void k_attn(
    const u16* __restrict__ q1p, const u16* __restrict__ q2p,
    const u16* __restrict__ k1p, const u16* __restrict__ k2p,
    const u16* __restrict__ vfp,
    const float* __restrict__ lq1, const float* __restrict__ lk1,
    const float* __restrict__ lq2, const float* __restrict__ lk2,
    u16* __restrict__ ybp) {
  __shared__ __align__(16) char smem[32768];  // 2 x (K1 4K | K2 4K | Vf 8K)
  const int fid = blockIdx.x;
  const int xcd = fid & 7;
  const int p = (fid >> 3) & 31;
  const int k = fid >> 8;                      // round 0..3
  const int t8 = p >> 2;
  const int tile = (k == 0) ? (31 - t8) : (k == 1) ? t8
                 : (k == 2) ? (23 - t8) : (8 + t8);
  const int bh = xcd * 4 + (p & 3);
  const int b = bh >> 4, h = bh & 15;
  const int tid = threadIdx.x, w = tid >> 6, l = tid & 63, g = l >> 4, q = l & 15;
  const int nchunk = 2 * tile + 2;             // 32-kv chunks
  const int qrow = tile * 64 + w * 16 + q;

  float a1 = lq1[h * 64 + l] * lk1[h * 64 + l];
  float a2 = lq2[h * 64 + l] * lk2[h * 64 + l];
#pragma unroll
  for (int off = 32; off; off >>= 1) {
    a1 += __shfl_xor(a1, off);
    a2 += __shfl_xor(a2, off);
  }
  const float lam = expf(a1) - expf(a2) + LAMBDA_INIT;

  short8 qf[2][2];
  {
    size_t qoff = ((size_t)bh * 2048 + qrow) * 64;
#pragma unroll
    for (int ks = 0; ks < 2; ++ks) {
      qf[0][ks] = *(const short8*)(q1p + qoff + ks * 32 + g * 8);
      qf[1][ks] = *(const short8*)(q2p + qoff + ks * 32 + g * 8);
    }
  }
  f32x4 o[2][8];
  float lsum[2] = {0.f, 0.f};
#pragma unroll
  for (int s = 0; s < 2; s++)
#pragma unroll
    for (int mt = 0; mt < 8; mt++) o[s][mt] = (f32x4){0.f, 0.f, 0.f, 0.f};

  auto stage_kv = [&](char* sb, int kv0) {
    int kv = tid >> 3, off = tid & 7;
    int sw = (off * 16) ^ ((kv & 7) << 4);
    size_t rb = ((size_t)bh * 2048 + kv0 + kv) * 128;
    gload16((const char*)k1p + rb + sw, sb + tid * 16);
    gload16((const char*)k2p + rb + sw, sb + 4096 + tid * 16);
    const char* vsrc = (const char*)vfp + (size_t)bh * 524288
                     + (size_t)(kv0 >> 6) * 16384 + (size_t)((kv0 >> 5) & 1) * 8192;
    gload16(vsrc + tid * 16, sb + 8192 + tid * 16);
    gload16(vsrc + 4096 + tid * 16, sb + 12288 + tid * 16);
  };

  stage_kv(smem, 0);

  for (int i = 0; i < nchunk; ++i) {
    char* sb = smem + (i & 1) * 16384;
    asm volatile("s_waitcnt vmcnt(0)" ::: "memory");
    __builtin_amdgcn_s_barrier();
    if (i + 1 < nchunk) stage_kv(smem + ((i + 1) & 1) * 16384, (i + 1) * 32);

    const int kv0 = i * 32;
    const bool diag = (i >= nchunk - 2);

    u32 pk[2][4];
#pragma unroll
    for (int s = 0; s < 2; ++s) {
      const char* Ks = sb + s * 4096;
      f32x4 s0 = {0.f, 0.f, 0.f, 0.f}, s1 = {0.f, 0.f, 0.f, 0.f};
#pragma unroll
      for (int ks = 0; ks < 2; ++ks) {
        short8 af0 = *(const short8*)(Ks + ((q * 128 + ks * 64 + g * 16) ^ ((q & 7) << 4)));
        short8 af1 = *(const short8*)(Ks + (((16 + q) * 128 + ks * 64 + g * 16) ^ ((q & 7) << 4)));
        s0 = __builtin_amdgcn_mfma_f32_16x16x32_bf16(af0, qf[s][ks], s0, 0, 0, 0);
        s1 = __builtin_amdgcn_mfma_f32_16x16x32_bf16(af1, qf[s][ks], s1, 0, 0, 0);
      }
      const int kb0 = kv0 + 4 * g, kb1 = kb0 + 16;
      if (diag) {
#pragma unroll
        for (int r = 0; r < 4; r++) {
          s0[r] = (kb0 + r > qrow) ? -1e30f : s0[r];
          s1[r] = (kb1 + r > qrow) ? -1e30f : s1[r];
        }
      }
      float p0[4], p1[4], rs = 0.f;
#pragma unroll
      for (int r = 0; r < 4; r++) {
        p0[r] = expv(s0[r]);
        p1[r] = expv(s1[r]);
        rs += p0[r] + p1[r];
      }
      lsum[s] += rs;  // per-lane partial; reduced in epilogue

      u32 pk0[2] = { packtr(p0[0], p0[1]), packtr(p0[2], p0[3]) };
      u32 pk1[2] = { packtr(p1[0], p1[1]), packtr(p1[2], p1[3]) };
      int srcA = q + (g & 1) * 32;
      int srcB = srcA + 16;
      u32 xa0 = (u32)__shfl((int)pk0[0], srcA), xa1 = (u32)__shfl((int)pk0[1], srcA);
      u32 xa2 = (u32)__shfl((int)pk0[0], srcB), xa3 = (u32)__shfl((int)pk0[1], srcB);
      u32 xb0 = (u32)__shfl((int)pk1[0], srcA), xb1 = (u32)__shfl((int)pk1[1], srcA);
      u32 xb2 = (u32)__shfl((int)pk1[0], srcB), xb3 = (u32)__shfl((int)pk1[1], srcB);
      bool lo = (g < 2);
      pk[s][0] = lo ? xa0 : xb0;
      pk[s][1] = lo ? xa1 : xb1;
      pk[s][2] = lo ? xa2 : xb2;
      pk[s][3] = lo ? xa3 : xb3;
    }
    u32x4 t0 = {pk[0][0], pk[0][1], pk[0][2], pk[0][3]};
    u32x4 t1 = {pk[1][0], pk[1][1], pk[1][2], pk[1][3]};
    short8 pf0 = __builtin_bit_cast(short8, t0);
    short8 pf1 = __builtin_bit_cast(short8, t1);
    const char* Vb = sb + 8192 + l * 16;
    __builtin_amdgcn_s_setprio(1);
#pragma unroll
    for (int mt = 0; mt < 8; ++mt) {
      short8 vf = *(const short8*)(Vb + mt * 1024);
      o[0][mt] = __builtin_amdgcn_mfma_f32_16x16x32_bf16(vf, pf0, o[0][mt], 0, 0, 0);
      o[1][mt] = __builtin_amdgcn_mfma_f32_16x16x32_bf16(vf, pf1, o[1][mt], 0, 0, 0);
    }
    __builtin_amdgcn_s_setprio(0);
  }

  float l0 = lsum[0]; l0 += __shfl_xor(l0, 16); l0 += __shfl_xor(l0, 32);
  float l1 = lsum[1]; l1 += __shfl_xor(l1, 16); l1 += __shfl_xor(l1, 32);
  const float inv0 = 1.f / l0, inv1 = 1.f / l1;
  float sum = 0.f, ssq = 0.f;
#pragma unroll
  for (int mt = 0; mt < 8; ++mt)
#pragma unroll
    for (int r = 0; r < 4; r++) {
      float y = o[0][mt][r] * inv0 - lam * (o[1][mt][r] * inv1);
      o[0][mt][r] = y;
      sum += y;
      ssq += y * y;
    }
  sum += __shfl_xor(sum, 16); sum += __shfl_xor(sum, 32);
  ssq += __shfl_xor(ssq, 16); ssq += __shfl_xor(ssq, 32);
  const float mean = sum * (1.f / 128.f);
  const float var = ssq * (1.f / 128.f) - mean * mean;
  const float rstd = rsqrtf(var + 1e-5f) * ONE_MINUS_LI;
  u16* dst = ybp + ((size_t)(b * 2048 + qrow)) * 2048 + h * 128;
#pragma unroll
  for (int mt = 0; mt < 8; ++mt) {
    u16x4 pv;
#pragma unroll
    for (int r = 0; r < 4; r++) pv[r] = f2bf((o[0][mt][r] - mean) * rstd);
    *(u16x4*)(dst + mt * 16 + 4 * g) = pv;
  }
}

// ---------------- output projection (512 thr, pipelined) ------------------
__global__ __launch_bounds__(512) void k_gemm_out(
    const u16* __restrict__ yb, const u16* __restrict__ wcb,
    float* __restrict__ out) {
  __shared__ __align__(16) char smem[65536];   // 2 x (As 16K | Bs 16K)
  const int tid = threadIdx.x;
  const int l = tid & 63, w = tid >> 6, g = l >> 4, q = l & 15;
  const int wm = w >> 1, wn = w & 1;   // wm 0..3 (32-row strips), wn 0..1 (64-col)
  const int n0 = blockIdx.x * 128, m0 = blockIdx.y * 128;
  f32x4 acc[2][4];
#pragma unroll
  for (int mi = 0; mi < 2; mi++)
#pragma unroll
    for (int ni = 0; ni < 4; ni++) acc[mi][ni] = (f32x4){0.f, 0.f, 0.f, 0.f};

  auto stage = [&](char* sb, int kt) {
#pragma unroll
    for (int i = 0; i < 2; i++) {
      int cc = i * 512 + tid;
      int row = cc >> 3, off = cc & 7;
      int sw = (off * 16) ^ ((row & 7) << 4);
      gload16((const char*)yb + ((size_t)(m0 + row) * 2048 + kt * 64) * 2 + sw, sb + cc * 16);
      gload16((const char*)wcb + ((size_t)(n0 + row) * 2048 + kt * 64) * 2 + sw, sb + 16384 + cc * 16);
    }
  };

  stage(smem, 0);
  for (int kt = 0; kt < 32; ++kt) {
    asm volatile("s_waitcnt vmcnt(0)" ::: "memory");
    __builtin_amdgcn_s_barrier();
    if (kt + 1 < 32) stage(smem + ((kt + 1) & 1) * 32768, kt + 1);
    const char* As = smem + (kt & 1) * 32768;
    const char* Bs = As + 16384;
#pragma unroll
    for (int ks = 0; ks < 2; ++ks) {
      short8 af[2], bf[4];
#pragma unroll
      for (int mi = 0; mi < 2; mi++) {
        int row = wm * 32 + mi * 16 + q;
        af[mi] = *(const short8*)(As + ((row * 128 + ks * 64 + g * 16) ^ ((row & 7) << 4)));
      }
#pragma unroll
      for (int ni = 0; ni < 4; ni++) {
        int row = wn * 64 + ni * 16 + q;
        bf[ni] = *(const short8*)(Bs + ((row * 128 + ks * 64 + g * 16) ^ ((row & 7) << 4)));
      }
#pragma unroll
      for (int mi = 0; mi < 2; mi++)
#pragma unroll
        for (int ni = 0; ni < 4; ni++)
          acc[mi][ni] = __builtin_amdgcn_mfma_f32_16x16x32_bf16(af[mi], bf[ni], acc[mi][ni], 0, 0, 0);
    }
  }
#pragma unroll
  for (int mi = 0; mi < 2; mi++)
#pragma unroll
    for (int ni = 0; ni < 4; ni++)
#pragma unroll
      for (int r = 0; r < 4; r++) {
        int row = m0 + wm * 32 + mi * 16 + 4 * g + r;
        int col = n0 + wn * 64 + ni * 16 + q;
        out[(size_t)row * 1024 + col] = acc[mi][ni][r];
      }
}

extern "C" void kernel_launch(void* const* d_in, const int* in_sizes, int n_in,
                              void* d_out, int out_size, void* d_ws, size_t ws_size,
                              hipStream_t stream) {
  const float* x   = (const float*)d_in[0];
  const float* Wq1 = (const float*)d_in[1];
  const float* Wq2 = (const float*)d_in[2];
  const float* Wk1 = (const float*)d_in[3];
  const float* Wk2 = (const float*)d_in[4];
  const float* Wv  = (const float*)d_in[5];
  const float* Wc  = (const float*)d_in[6];
  const float* lq1 = (const float*)d_in[7];
  const float* lk1 = (const float*)d_in[8];
  const float* lq2 = (const float*)d_in[9];
  const float* lk2 = (const float*)d_in[10];

  char* ws = (char*)d_ws;
  u16* xb   = (u16*)(ws);                    // 8 MB
  u16* wall = (u16*)(ws + 8388608);          // 12 MB
  u16* wcb  = (u16*)(ws + 20971520);         // 4 MB
  u16* q1   = (u16*)(ws + 25165824);         // 8 MB
  u16* q2   = (u16*)(ws + 33554432);         // 8 MB
  u16* k1   = (u16*)(ws + 41943040);         // 8 MB
  u16* k2   = (u16*)(ws + 50331648);         // 8 MB
  u16* vt   = (u16*)(ws + 58720256);         // 16 MB (x32-fragment-packed Vf)
  u16* yb   = (u16*)(ws + 75497472);         // 16 MB

  k_cvt12<<<dim3(1024, 12), 256, 0, stream>>>(x, Wq1, Wq2, Wk1, Wk2, Wv, Wc,
                                              xb, wall, wcb);
  k_gemm_qkv<<<dim3(48, 32), 256, 0, stream>>>(xb, wall, q1, q2, k1, k2, vt);
  k_attn<<<1024, 256, 0, stream>>>(q1, q2, k1, k2, vt,
                                   lq1, lk1, lq2, lk2, yb);
  k_gemm_out<<<dim3(8, 32), 512, 0, stream>>>(yb, wcb, (float*)d_out);
}